// Round 11
// baseline (1312.910 us; speedup 1.0000x reference)
//
#include <hip/hip_runtime.h>
#include <hip/hip_bf16.h>

#define BATCH 8
#define N1 4096
#define N2 2048
#define HID 64
#define KNN 8
#define INDIM 10

using u64 = unsigned long long;

// Scratch in static device memory (~46 MB): d_ws size is not guaranteed.
// Every buffer is fully rewritten each call (or re-initialized by init_kernel).
__device__ __align__(256) float    g_h1[BATCH * N1 * HID];
__device__ __align__(256) float    g_h2[BATCH * N2 * HID];
__device__ __align__(256) float    g_x2n[BATCH * N1];
__device__ __align__(256) float    g_x2n2[BATCH * N2];
__device__ __align__(256) int      g_nbr[BATCH * N1 * KNN];
__device__ __align__(256) float    g_uu[BATCH * N1 * 96];
__device__ __align__(256) float    g_vv[BATCH * N1 * 96];
__device__ __align__(256) unsigned g_ek1[BATCH * N1 * HID];
__device__ __align__(256) unsigned g_ek2[BATCH * N2 * HID];

__device__ __forceinline__ float eluf(float x) { return x > 0.f ? x : __expf(x) - 1.f; }
// order-isomorphic float->u32 encoding: a<b  <=>  enc(a)<enc(b) (unsigned)
__device__ __forceinline__ unsigned encf(float f) {
  unsigned u = __float_as_uint(f);
  return (u & 0x80000000u) ? ~u : (u | 0x80000000u);
}
__device__ __forceinline__ float decf(unsigned k) {
  unsigned u = (k & 0x80000000u) ? (k & 0x7FFFFFFFu) : ~k;
  return __uint_as_float(u);
}
// encf(-1.0f): ELU outputs are strictly > -1 => legal max-identity.
#define ENC_NEG1 0x407FFFFFu
__device__ __forceinline__ unsigned enc_safe(float v) {
  if (!(v == v)) return ENC_NEG1;
  return encf(v);
}
__device__ __forceinline__ float dec_safe(unsigned k) {
  float v = decf(k);
  if (!(v == v)) return -1.0f;
  return fminf(fmaxf(v, -3.0e38f), 3.0e38f);
}

// ---------------- init the scatter-max accumulators --------------------------
__global__ __launch_bounds__(256) void init_kernel() {
  int t = blockIdx.x * 256 + threadIdx.x;
  uint4 z = make_uint4(ENC_NEG1, ENC_NEG1, ENC_NEG1, ENC_NEG1);
  const int n1 = BATCH * N1 * HID / 4;
  if (t < n1) ((uint4*)g_ek1)[t] = z;
  else ((uint4*)g_ek2)[t - n1] = z;
}

// ---------------- input MLP: x*norm -> 32 (elu) -> 64 (elu), plus |h|^2 ------
__global__ __launch_bounds__(256) void input_mlp(
    const float* __restrict__ x, const float* __restrict__ norm,
    const float* __restrict__ w1g, const float* __restrict__ b1g,
    const float* __restrict__ w2g, const float* __restrict__ b2g) {
  __shared__ float sw1[320], sb1[32], sw2[2048], sb2[64], snorm[INDIM];
  int t = threadIdx.x;
  for (int q = t; q < 320; q += 256) sw1[q] = w1g[q];
  for (int q = t; q < 2048; q += 256) sw2[q] = w2g[q];
  if (t < 32) sb1[t] = b1g[t];
  if (t < 64) sb2[t] = b2g[t];
  if (t < INDIM) snorm[t] = norm[t];
  __syncthreads();
  int node = blockIdx.x * 256 + t;  // < BATCH*N1
  float xv[INDIM];
#pragma unroll
  for (int d = 0; d < INDIM; ++d)
    xv[d] = x[(size_t)node * INDIM + d] * snorm[d];
  float t1[32];
#pragma unroll
  for (int c = 0; c < 32; ++c) {
    float acc = sb1[c];
#pragma unroll
    for (int d = 0; d < INDIM; ++d) acc += xv[d] * sw1[d * 32 + c];
    t1[c] = eluf(acc);
  }
  float* hr = g_h1 + (size_t)node * HID;
  float sq = 0.f;
#pragma unroll
  for (int c = 0; c < HID; ++c) {
    float acc = sb2[c];
#pragma unroll
    for (int d = 0; d < 32; ++d) acc += t1[d] * sw2[d * HID + c];
    float v = eluf(acc);
    hr[c] = v;
    sq += v * v;
  }
  g_x2n[node] = sq;
}

// ---------------- brute-force kNN (k=8) on u64 keys --------------------------
// LANE = i-ROW layout: each lane holds its own h-row in 64 VGPRs; the j index
// is wave-uniform (wave id via readfirstlane), so the j-row loads scalarize to
// s_load into SGPRs and broadcast into v_fma via the scalar operand port --
// ZERO hot-loop VMEM lane traffic (the r9/r10 bottleneck: same-address wave
// loads cost ~16 cyc each in the TA unit). FMA grouping (a0..a3, stride 4,
// (a0+a1)+(a2+a3), full x2i+x2j-2s form) matches r10 bit-exactly, so the
// u64-key top-8 (NaN-safe, tie -> lower j, partition-order invariant) gives
// identical neighbor sets.
template <int LEVEL>
__global__ __launch_bounds__(256, 2) void knn_kernel() {
  __shared__ u64 lk[256 * KNN];  // 16 KB
  constexpr int n = LEVEL ? N2 : N1;
  constexpr int SPLIT = 4;  // 4 waves = 4 j-splits per block
  const float* __restrict__ h = LEVEL ? g_h2 : g_h1;
  const float* __restrict__ x2 = LEVEL ? g_x2n2 : g_x2n;
  int b = blockIdx.x & 7;  // XCD-friendly batch swizzle
  int t = threadIdx.x;
  int lane = t & 63;
  int s = __builtin_amdgcn_readfirstlane(t >> 6);  // wave id -> SGPR (uniform)
  int i = (blockIdx.x >> 3) * 64 + lane;           // row per lane
  const float* __restrict__ hb = h + (size_t)b * n * HID;
  const float* __restrict__ x2b = x2 + (size_t)b * n;
  float hi[HID];
  {
    const float4* hr = (const float4*)(hb + (size_t)i * HID);
#pragma unroll
    for (int q = 0; q < 16; ++q) {
      float4 v = hr[q];
      hi[4 * q] = v.x; hi[4 * q + 1] = v.y; hi[4 * q + 2] = v.z; hi[4 * q + 3] = v.w;
    }
  }
  float x2i = x2b[i];
  u64 best[KNN];
#pragma unroll
  for (int p = 0; p < KNN; ++p) best[p] = ~0ull;
  constexpr int nper = n / SPLIT;
  int j0 = s * nper;
  for (int jj = 0; jj < nper; ++jj) {
    int j = j0 + jj;  // wave-uniform
    const float* __restrict__ hj = hb + (size_t)j * HID;  // uniform -> s_load
    float a0 = 0.f, a1 = 0.f, a2 = 0.f, a3 = 0.f;
#pragma unroll
    for (int q = 0; q < 16; ++q) {
      a0 += hi[4 * q] * hj[4 * q];
      a1 += hi[4 * q + 1] * hj[4 * q + 1];
      a2 += hi[4 * q + 2] * hj[4 * q + 2];
      a3 += hi[4 * q + 3] * hj[4 * q + 3];
    }
    float dd = x2i + x2b[j] - 2.f * ((a0 + a1) + (a2 + a3));
    u64 key = ((u64)encf(dd) << 32) | (unsigned)j;
    if (j != i && key < best[KNN - 1]) {
      u64 ck = key;
#pragma unroll
      for (int p = 0; p < KNN; ++p) {
        u64 ob = best[p];
        bool ex = ob < ck;
        best[p] = ex ? ob : ck;
        ck = ex ? ck : ob;
      }
    }
  }
#pragma unroll
  for (int p = 0; p < KNN; ++p) lk[t * KNN + p] = best[p];
  __syncthreads();
  if (s == 0) {
    for (int os = 1; os < SPLIT; ++os) {
      int tt = os * 64 + lane;
#pragma unroll
      for (int p = 0; p < KNN; ++p) {
        u64 ck = lk[tt * KNN + p];
        if (ck < best[KNN - 1]) {
#pragma unroll
          for (int p2 = 0; p2 < KNN; ++p2) {
            u64 ob = best[p2];
            bool ex = ob < ck;
            best[p2] = ex ? ob : ck;
            ck = ex ? ck : ob;
          }
        }
      }
    }
    int* ob = g_nbr + ((size_t)b * n + i) * KNN;
#pragma unroll
    for (int p = 0; p < KNN; ++p) ob[p] = (int)(best[p] & (u64)(n - 1));
  }
}

// ---------------- per-node u/v for EdgeConv layer-1 factorization ------------
// [x_d, x_s-x_d]@W1+b1 = u_d + v_s with u = x@(Wtop-Wbot)+b1, v = x@Wbot.
// block = 64 nodes x 4 col-chunks (24 cols each; chunk == wave -> uniform).
__global__ __launch_bounds__(256) void uv_kernel(int level,
                                                 const float* __restrict__ w1g,
                                                 const float* __restrict__ b1g) {
  __shared__ float sw1[128 * 96];  // 48 KB
  __shared__ float sb1[96];
  int t = threadIdx.x;
  for (int q = t; q < 128 * 96; q += 256) sw1[q] = w1g[q];
  if (t < 96) sb1[t] = b1g[t];
  __syncthreads();
  const int n = level ? N2 : N1;
  const float* h = level ? g_h2 : g_h1;
  int b = blockIdx.x & 7;
  int nl = (blockIdx.x >> 3) * 64 + (t & 63);
  int c0 = (t >> 6) * 24;  // wave-uniform chunk
  size_t node = (size_t)b * n + nl;
  const float4* h4 = (const float4*)(h + node * HID);
  float hv[HID];
#pragma unroll
  for (int q = 0; q < 16; ++q) {
    float4 vv = h4[q];
    hv[4 * q] = vv.x; hv[4 * q + 1] = vv.y; hv[4 * q + 2] = vv.z; hv[4 * q + 3] = vv.w;
  }
  float ua[24], va[24];
#pragma unroll
  for (int c = 0; c < 24; ++c) { ua[c] = 0.f; va[c] = 0.f; }
  for (int d = 0; d < HID; ++d) {
    float hd = hv[d];
    const float* wt = sw1 + d * 96 + c0;        // wave-uniform -> broadcast
    const float* wb = sw1 + (HID + d) * 96 + c0;
#pragma unroll
    for (int c = 0; c < 24; ++c) {
      ua[c] += hd * wt[c];
      va[c] += hd * wb[c];
    }
  }
  float* ur = g_uu + node * 96 + c0;
  float* vr = g_vv + node * 96 + c0;
#pragma unroll
  for (int c = 0; c < 24; ++c) {
    ur[c] = ua[c] - va[c] + sb1[c0 + c];
    vr[c] = va[c];
  }
}

// ---------------- edge messages + max scatter (wave-per-node) ----------------
// Wave owns node i; lane = output channel. Per neighbor: stage tv[96] vectors
// in LDS (forward u_i+v_j, reverse u_j+v_i), then lane-parallel 96-step FMA.
// Forward messages max-reduce in a register (1 atomic run/node); reverse
// scatters to j, skipped when the edge is mutual (identical value produced by
// j's own forward pass). One scalar accumulator per lane -> no scratch spill.
__global__ __launch_bounds__(256) void edge_kernel(int level,
                                                   const float* __restrict__ w2g,
                                                   const float* __restrict__ b2g) {
  __shared__ __align__(16) float sw2[96 * 64];  // 24 KB, [kk][o]
  __shared__ float sb2[64];
  __shared__ __align__(16) float stA[4][96], stB[4][96];  // per-wave tv vectors
  int t = threadIdx.x;
  for (int q = t; q < 96 * 64; q += 256) sw2[q] = w2g[q];
  if (t < 64) sb2[t] = b2g[t];
  __syncthreads();
  const int n = level ? N2 : N1;
  unsigned* ekey = level ? g_ek2 : g_ek1;
  int b = blockIdx.x & 7;  // XCD swizzle
  int wv = t >> 6, lane = t & 63;
  int i = (blockIdx.x >> 3) * 4 + wv;  // wave-uniform node
  const int* nbb = g_nbr + (size_t)b * n * KNN;
  const float* ub = g_uu + (size_t)b * n * 96;
  const float* vb = g_vv + (size_t)b * n * 96;
  unsigned* eb = ekey + (size_t)b * n * HID;
  float ui0 = ub[(size_t)i * 96 + lane];
  float vi0 = vb[(size_t)i * 96 + lane];
  float ui1 = 0.f, vi1 = 0.f;
  if (lane < 32) {
    ui1 = ub[(size_t)i * 96 + 64 + lane];
    vi1 = vb[(size_t)i * 96 + 64 + lane];
  }
  const float biasv = sb2[lane];
  float macc = -1.0f;
  for (int k = 0; k < KNN; ++k) {
    __syncthreads();  // protect prev iteration's tv reads before overwrite
    int j = nbb[(size_t)i * KNN + k] & (n - 1);  // wave-uniform
    bool needB = true;
#pragma unroll
    for (int k2 = 0; k2 < KNN; ++k2)
      needB = needB && ((nbb[(size_t)j * KNN + k2] & (n - 1)) != i);
    {
      float vj0 = vb[(size_t)j * 96 + lane];
      float uj0 = ub[(size_t)j * 96 + lane];
      stA[wv][lane] = eluf(ui0 + vj0);
      if (needB) stB[wv][lane] = eluf(uj0 + vi0);
      if (lane < 32) {
        float vj1 = vb[(size_t)j * 96 + 64 + lane];
        float uj1 = ub[(size_t)j * 96 + 64 + lane];
        stA[wv][64 + lane] = eluf(ui1 + vj1);
        if (needB) stB[wv][64 + lane] = eluf(uj1 + vi1);
      }
    }
    __syncthreads();  // make tv visible across lanes
    float a0 = 0.f, a1 = 0.f, b0 = 0.f, b1 = 0.f;
    if (needB) {
      for (int kk = 0; kk < 96; kk += 4) {
        float4 ta = *(const float4*)&stA[wv][kk];
        float4 tb = *(const float4*)&stB[wv][kk];
        float w0 = sw2[(kk + 0) * 64 + lane];
        float w1 = sw2[(kk + 1) * 64 + lane];
        float w2v = sw2[(kk + 2) * 64 + lane];
        float w3 = sw2[(kk + 3) * 64 + lane];
        a0 += ta.x * w0 + ta.y * w1;
        a1 += ta.z * w2v + ta.w * w3;
        b0 += tb.x * w0 + tb.y * w1;
        b1 += tb.z * w2v + tb.w * w3;
      }
      atomicMax(&eb[(size_t)j * HID + lane],
                enc_safe(eluf(biasv + b0 + b1)));
    } else {
      for (int kk = 0; kk < 96; kk += 4) {
        float4 ta = *(const float4*)&stA[wv][kk];
        float w0 = sw2[(kk + 0) * 64 + lane];
        float w1 = sw2[(kk + 1) * 64 + lane];
        float w2v = sw2[(kk + 2) * 64 + lane];
        float w3 = sw2[(kk + 3) * 64 + lane];
        a0 += ta.x * w0 + ta.y * w1;
        a1 += ta.z * w2v + ta.w * w3;
      }
    }
    macc = fmaxf(macc, eluf(biasv + a0 + a1));
  }
  atomicMax(&eb[(size_t)i * HID + lane], enc_safe(macc));
}

// ---------------- pairwise max pool + norms ----------------------------------
__global__ __launch_bounds__(256) void pool_kernel() {
  int node = blockIdx.x * 256 + threadIdx.x;  // < BATCH*N2
  int b = node >> 11;
  int m = node & (N2 - 1);
  const unsigned* e = g_ek1 + ((size_t)b * N1 + 2 * m) * HID;
  float* hr = g_h2 + (size_t)node * HID;
  float sq = 0.f;
#pragma unroll
  for (int d = 0; d < HID; ++d) {
    float mx = fmaxf(dec_safe(e[d]), dec_safe(e[HID + d]));
    hr[d] = mx;
    sq += mx * mx;
  }
  g_x2n2[node] = sq;
}

// ---------------- global max + output MLP -> FLOAT32 output ------------------
__global__ __launch_bounds__(64) void final_kernel(
    const float* __restrict__ wo1, const float* __restrict__ bo1,
    const float* __restrict__ wo2, const float* __restrict__ bo2,
    const float* __restrict__ wo3, const float* __restrict__ bo3,
    float* __restrict__ out) {
  __shared__ float g[HID];
  __shared__ float o1s[HID];
  __shared__ float o2s[32];
  int b = blockIdx.x;
  int t = threadIdx.x;  // 0..63
  const unsigned* e = g_ek2 + (size_t)b * N2 * HID;
  unsigned mk = 0u;
  for (int m = 0; m < N2; ++m) {
    unsigned q = e[(size_t)m * HID + t];
    mk = q > mk ? q : mk;
  }
  g[t] = dec_safe(mk);
  __syncthreads();
  {
    float a1 = bo1[t];
    for (int d = 0; d < HID; ++d) a1 += g[d] * wo1[d * HID + t];
    o1s[t] = eluf(a1);
  }
  __syncthreads();
  if (t < 32) {
    float a2 = bo2[t];
    for (int d = 0; d < HID; ++d) a2 += o1s[d] * wo2[d * 32 + t];
    o2s[t] = eluf(a2);
  }
  __syncthreads();
  if (t == 0) {
    float acc0 = bo3[0];
    float acc1 = bo3[1];
    for (int d = 0; d < 32; ++d) {
      acc0 += o2s[d] * wo3[d * 2 + 0];
      acc1 += o2s[d] * wo3[d * 2 + 1];
    }
    float met = fmaxf(acc0, 0.f) + log1pf(expf(-fabsf(acc0)));      // softplus
    float phi = 3.14159265358979f * (2.f / (1.f + expf(-acc1)) - 1.f);
    out[b * 2 + 0] = met;
    out[b * 2 + 1] = phi;
  }
}

extern "C" void kernel_launch(void* const* d_in, const int* in_sizes, int n_in,
                              void* d_out, int out_size, void* d_ws,
                              size_t ws_size, hipStream_t stream) {
  const float* x     = (const float*)d_in[0];
  const float* dnorm = (const float*)d_in[1];
  const float* w_in1 = (const float*)d_in[2];
  const float* b_in1 = (const float*)d_in[3];
  const float* w_in2 = (const float*)d_in[4];
  const float* b_in2 = (const float*)d_in[5];
  const float* w_c1a = (const float*)d_in[6];
  const float* b_c1a = (const float*)d_in[7];
  const float* w_c1b = (const float*)d_in[8];
  const float* b_c1b = (const float*)d_in[9];
  const float* w_c2a = (const float*)d_in[10];
  const float* b_c2a = (const float*)d_in[11];
  const float* w_c2b = (const float*)d_in[12];
  const float* b_c2b = (const float*)d_in[13];
  const float* w_o1  = (const float*)d_in[14];
  const float* b_o1  = (const float*)d_in[15];
  const float* w_o2  = (const float*)d_in[16];
  const float* b_o2  = (const float*)d_in[17];
  const float* w_o3  = (const float*)d_in[18];
  const float* b_o3  = (const float*)d_in[19];

  init_kernel<<<(BATCH * N1 * HID + BATCH * N2 * HID) / 4 / 256, 256, 0,
                stream>>>();
  input_mlp<<<BATCH * N1 / 256, 256, 0, stream>>>(x, dnorm, w_in1, b_in1,
                                                  w_in2, b_in2);
  knn_kernel<0><<<8 * (N1 / 64), 256, 0, stream>>>();
  uv_kernel<<<8 * (N1 / 64), 256, 0, stream>>>(0, w_c1a, b_c1a);
  edge_kernel<<<8 * (N1 / 4), 256, 0, stream>>>(0, w_c1b, b_c1b);
  pool_kernel<<<BATCH * N2 / 256, 256, 0, stream>>>();
  knn_kernel<1><<<8 * (N2 / 64), 256, 0, stream>>>();
  uv_kernel<<<8 * (N2 / 64), 256, 0, stream>>>(1, w_c2a, b_c2a);
  edge_kernel<<<8 * (N2 / 4), 256, 0, stream>>>(1, w_c2b, b_c2b);
  final_kernel<<<BATCH, 64, 0, stream>>>(w_o1, b_o1, w_o2, b_o2, w_o3, b_o3,
                                         (float*)d_out);
}

// Round 12
// 1233.715 us; speedup vs baseline: 1.0642x; 1.0642x over previous
//
#include <hip/hip_runtime.h>
#include <hip/hip_bf16.h>

#define BATCH 8
#define N1 4096
#define N2 2048
#define HID 64
#define KNN 8
#define INDIM 10

using u64 = unsigned long long;

// Scratch in static device memory (~46 MB): d_ws size is not guaranteed.
// Every buffer is fully rewritten each call (or re-initialized by init_kernel).
__device__ __align__(256) float    g_h1[BATCH * N1 * HID];
__device__ __align__(256) float    g_h2[BATCH * N2 * HID];
__device__ __align__(256) float    g_x2n[BATCH * N1];
__device__ __align__(256) float    g_x2n2[BATCH * N2];
__device__ __align__(256) int      g_nbr[BATCH * N1 * KNN];
__device__ __align__(256) float    g_uu[BATCH * N1 * 96];
__device__ __align__(256) float    g_vv[BATCH * N1 * 96];
__device__ __align__(256) unsigned g_ek1[BATCH * N1 * HID];
__device__ __align__(256) unsigned g_ek2[BATCH * N2 * HID];

__device__ __forceinline__ float eluf(float x) { return x > 0.f ? x : __expf(x) - 1.f; }
// order-isomorphic float->u32 encoding: a<b  <=>  enc(a)<enc(b) (unsigned)
__device__ __forceinline__ unsigned encf(float f) {
  unsigned u = __float_as_uint(f);
  return (u & 0x80000000u) ? ~u : (u | 0x80000000u);
}
__device__ __forceinline__ float decf(unsigned k) {
  unsigned u = (k & 0x80000000u) ? (k & 0x7FFFFFFFu) : ~k;
  return __uint_as_float(u);
}
// encf(-1.0f): ELU outputs are strictly > -1 => legal max-identity.
#define ENC_NEG1 0x407FFFFFu
__device__ __forceinline__ unsigned enc_safe(float v) {
  if (!(v == v)) return ENC_NEG1;
  return encf(v);
}
__device__ __forceinline__ float dec_safe(unsigned k) {
  float v = decf(k);
  if (!(v == v)) return -1.0f;
  return fminf(fmaxf(v, -3.0e38f), 3.0e38f);
}

// ---------------- init the scatter-max accumulators --------------------------
__global__ __launch_bounds__(256) void init_kernel() {
  int t = blockIdx.x * 256 + threadIdx.x;
  uint4 z = make_uint4(ENC_NEG1, ENC_NEG1, ENC_NEG1, ENC_NEG1);
  const int n1 = BATCH * N1 * HID / 4;
  if (t < n1) ((uint4*)g_ek1)[t] = z;
  else ((uint4*)g_ek2)[t - n1] = z;
}

// ---------------- input MLP: x*norm -> 32 (elu) -> 64 (elu), plus |h|^2 ------
__global__ __launch_bounds__(256) void input_mlp(
    const float* __restrict__ x, const float* __restrict__ norm,
    const float* __restrict__ w1g, const float* __restrict__ b1g,
    const float* __restrict__ w2g, const float* __restrict__ b2g) {
  __shared__ float sw1[320], sb1[32], sw2[2048], sb2[64], snorm[INDIM];
  int t = threadIdx.x;
  for (int q = t; q < 320; q += 256) sw1[q] = w1g[q];
  for (int q = t; q < 2048; q += 256) sw2[q] = w2g[q];
  if (t < 32) sb1[t] = b1g[t];
  if (t < 64) sb2[t] = b2g[t];
  if (t < INDIM) snorm[t] = norm[t];
  __syncthreads();
  int node = blockIdx.x * 256 + t;  // < BATCH*N1
  float xv[INDIM];
#pragma unroll
  for (int d = 0; d < INDIM; ++d)
    xv[d] = x[(size_t)node * INDIM + d] * snorm[d];
  float t1[32];
#pragma unroll
  for (int c = 0; c < 32; ++c) {
    float acc = sb1[c];
#pragma unroll
    for (int d = 0; d < INDIM; ++d) acc += xv[d] * sw1[d * 32 + c];
    t1[c] = eluf(acc);
  }
  float* hr = g_h1 + (size_t)node * HID;
  float sq = 0.f;
#pragma unroll
  for (int c = 0; c < HID; ++c) {
    float acc = sb2[c];
#pragma unroll
    for (int d = 0; d < 32; ++d) acc += t1[d] * sw2[d * HID + c];
    float v = eluf(acc);
    hr[c] = v;
    sq += v * v;
  }
  g_x2n[node] = sq;
}

// ---------------- brute-force kNN (k=8) on u64 keys --------------------------
// LANE = i-ROW layout, j-row via scalar pipe (wave-uniform j -> s_load,
// broadcast through the scalar operand port: zero hot-loop VMEM). r11 showed
// the SGPR file can't double-buffer the j-row (no pipelining), so the s_load
// wait (~200cy L2) is covered by ILP instead: ROWS=2 rows per lane doubles
// VALU per j (256cy), and 512-thread blocks keep 2 waves/SIMD. Distance
// expression and u64-key top-8 identical to r10/r11 -> bit-exact neighbors.
template <int LEVEL, int ROWS>
__global__ __launch_bounds__(512, 2) void knn_kernel() {
  constexpr int n = LEVEL ? N2 : N1;
  constexpr int SPLIT = 8;  // 8 waves = 8 j-splits per block
  constexpr int RPB = 64 * ROWS;
  __shared__ u64 lk[512 * ROWS * KNN];  // ROWS=2: 64KB, ROWS=1: 32KB
  const float* __restrict__ h = LEVEL ? g_h2 : g_h1;
  const float* __restrict__ x2 = LEVEL ? g_x2n2 : g_x2n;
  int b = blockIdx.x & 7;  // XCD-friendly batch swizzle
  int t = threadIdx.x;
  int lane = t & 63;
  int s = __builtin_amdgcn_readfirstlane(t >> 6);  // wave id -> SGPR
  int i0 = (blockIdx.x >> 3) * RPB + lane;
  int i1 = i0 + 64;  // used when ROWS==2
  const float* __restrict__ hb = h + (size_t)b * n * HID;
  const float* __restrict__ x2b = x2 + (size_t)b * n;
  float hi0[HID], hi1[ROWS == 2 ? HID : 1];
  {
    const float4* hr0 = (const float4*)(hb + (size_t)i0 * HID);
#pragma unroll
    for (int q = 0; q < 16; ++q) {
      float4 v = hr0[q];
      hi0[4 * q] = v.x; hi0[4 * q + 1] = v.y; hi0[4 * q + 2] = v.z; hi0[4 * q + 3] = v.w;
    }
    if (ROWS == 2) {
      const float4* hr1 = (const float4*)(hb + (size_t)i1 * HID);
#pragma unroll
      for (int q = 0; q < 16; ++q) {
        float4 v = hr1[q];
        hi1[4 * q] = v.x; hi1[4 * q + 1] = v.y; hi1[4 * q + 2] = v.z; hi1[4 * q + 3] = v.w;
      }
    }
  }
  float x2i0 = x2b[i0];
  float x2i1 = ROWS == 2 ? x2b[i1] : 0.f;
  u64 best0[KNN], best1[KNN];
#pragma unroll
  for (int p = 0; p < KNN; ++p) { best0[p] = ~0ull; best1[p] = ~0ull; }
  constexpr int nper = n / SPLIT;
  int j0 = s * nper;
  for (int jj = 0; jj < nper; ++jj) {
    int j = j0 + jj;  // wave-uniform
    const float* __restrict__ hj = hb + (size_t)j * HID;  // uniform -> s_load
    float a0 = 0.f, a1 = 0.f, a2 = 0.f, a3 = 0.f;
    float c0 = 0.f, c1 = 0.f, c2 = 0.f, c3 = 0.f;
#pragma unroll
    for (int q = 0; q < 16; ++q) {
      float w0 = hj[4 * q], w1 = hj[4 * q + 1], w2 = hj[4 * q + 2], w3 = hj[4 * q + 3];
      a0 += hi0[4 * q] * w0;
      a1 += hi0[4 * q + 1] * w1;
      a2 += hi0[4 * q + 2] * w2;
      a3 += hi0[4 * q + 3] * w3;
      if (ROWS == 2) {
        c0 += hi1[4 * q] * w0;
        c1 += hi1[4 * q + 1] * w1;
        c2 += hi1[4 * q + 2] * w2;
        c3 += hi1[4 * q + 3] * w3;
      }
    }
    float x2j = x2b[j];
    {
      float dd = x2i0 + x2j - 2.f * ((a0 + a1) + (a2 + a3));
      u64 key = ((u64)encf(dd) << 32) | (unsigned)j;
      if (j != i0 && key < best0[KNN - 1]) {
        u64 ck = key;
#pragma unroll
        for (int p = 0; p < KNN; ++p) {
          u64 ob = best0[p];
          bool ex = ob < ck;
          best0[p] = ex ? ob : ck;
          ck = ex ? ck : ob;
        }
      }
    }
    if (ROWS == 2) {
      float dd = x2i1 + x2j - 2.f * ((c0 + c1) + (c2 + c3));
      u64 key = ((u64)encf(dd) << 32) | (unsigned)j;
      if (j != i1 && key < best1[KNN - 1]) {
        u64 ck = key;
#pragma unroll
        for (int p = 0; p < KNN; ++p) {
          u64 ob = best1[p];
          bool ex = ob < ck;
          best1[p] = ex ? ob : ck;
          ck = ex ? ck : ob;
        }
      }
    }
  }
#pragma unroll
  for (int p = 0; p < KNN; ++p) {
    lk[t * KNN + p] = best0[p];
    if (ROWS == 2) lk[(512 + t) * KNN + p] = best1[p];
  }
  __syncthreads();
  if (s == 0) {
    for (int os = 1; os < SPLIT; ++os) {
      int tt = os * 64 + lane;
#pragma unroll
      for (int p = 0; p < KNN; ++p) {
        u64 ck = lk[tt * KNN + p];
        if (ck < best0[KNN - 1]) {
#pragma unroll
          for (int p2 = 0; p2 < KNN; ++p2) {
            u64 ob = best0[p2];
            bool ex = ob < ck;
            best0[p2] = ex ? ob : ck;
            ck = ex ? ck : ob;
          }
        }
        if (ROWS == 2) {
          u64 dk = lk[(512 + tt) * KNN + p];
          if (dk < best1[KNN - 1]) {
#pragma unroll
            for (int p2 = 0; p2 < KNN; ++p2) {
              u64 ob = best1[p2];
              bool ex = ob < dk;
              best1[p2] = ex ? ob : dk;
              dk = ex ? dk : ob;
            }
          }
        }
      }
    }
    int* ob0 = g_nbr + ((size_t)b * n + i0) * KNN;
#pragma unroll
    for (int p = 0; p < KNN; ++p) ob0[p] = (int)(best0[p] & (u64)(n - 1));
    if (ROWS == 2) {
      int* ob1 = g_nbr + ((size_t)b * n + i1) * KNN;
#pragma unroll
      for (int p = 0; p < KNN; ++p) ob1[p] = (int)(best1[p] & (u64)(n - 1));
    }
  }
}

// ---------------- per-node u/v for EdgeConv layer-1 factorization ------------
// [x_d, x_s-x_d]@W1+b1 = u_d + v_s with u = x@(Wtop-Wbot)+b1, v = x@Wbot.
// block = 64 nodes x 4 col-chunks (24 cols each; chunk == wave -> uniform).
__global__ __launch_bounds__(256) void uv_kernel(int level,
                                                 const float* __restrict__ w1g,
                                                 const float* __restrict__ b1g) {
  __shared__ float sw1[128 * 96];  // 48 KB
  __shared__ float sb1[96];
  int t = threadIdx.x;
  for (int q = t; q < 128 * 96; q += 256) sw1[q] = w1g[q];
  if (t < 96) sb1[t] = b1g[t];
  __syncthreads();
  const int n = level ? N2 : N1;
  const float* h = level ? g_h2 : g_h1;
  int b = blockIdx.x & 7;
  int nl = (blockIdx.x >> 3) * 64 + (t & 63);
  int c0 = (t >> 6) * 24;  // wave-uniform chunk
  size_t node = (size_t)b * n + nl;
  const float4* h4 = (const float4*)(h + node * HID);
  float hv[HID];
#pragma unroll
  for (int q = 0; q < 16; ++q) {
    float4 vv = h4[q];
    hv[4 * q] = vv.x; hv[4 * q + 1] = vv.y; hv[4 * q + 2] = vv.z; hv[4 * q + 3] = vv.w;
  }
  float ua[24], va[24];
#pragma unroll
  for (int c = 0; c < 24; ++c) { ua[c] = 0.f; va[c] = 0.f; }
  for (int d = 0; d < HID; ++d) {
    float hd = hv[d];
    const float* wt = sw1 + d * 96 + c0;        // wave-uniform -> broadcast
    const float* wb = sw1 + (HID + d) * 96 + c0;
#pragma unroll
    for (int c = 0; c < 24; ++c) {
      ua[c] += hd * wt[c];
      va[c] += hd * wb[c];
    }
  }
  float* ur = g_uu + node * 96 + c0;
  float* vr = g_vv + node * 96 + c0;
#pragma unroll
  for (int c = 0; c < 24; ++c) {
    ur[c] = ua[c] - va[c] + sb1[c0 + c];
    vr[c] = va[c];
  }
}

// ---------------- edge messages + max scatter (wave-per-node) ----------------
// Wave owns node i; lane = output channel. Per neighbor: stage tv[96] vectors
// in LDS (forward u_i+v_j, reverse u_j+v_i), then lane-parallel 96-step FMA.
// Forward messages max-reduce in a register (1 atomic run/node); reverse
// scatters to j, skipped when the edge is mutual (identical value produced by
// j's own forward pass). One scalar accumulator per lane -> no scratch spill.
__global__ __launch_bounds__(256) void edge_kernel(int level,
                                                   const float* __restrict__ w2g,
                                                   const float* __restrict__ b2g) {
  __shared__ __align__(16) float sw2[96 * 64];  // 24 KB, [kk][o]
  __shared__ float sb2[64];
  __shared__ __align__(16) float stA[4][96], stB[4][96];  // per-wave tv vectors
  int t = threadIdx.x;
  for (int q = t; q < 96 * 64; q += 256) sw2[q] = w2g[q];
  if (t < 64) sb2[t] = b2g[t];
  __syncthreads();
  const int n = level ? N2 : N1;
  unsigned* ekey = level ? g_ek2 : g_ek1;
  int b = blockIdx.x & 7;  // XCD swizzle
  int wv = t >> 6, lane = t & 63;
  int i = (blockIdx.x >> 3) * 4 + wv;  // wave-uniform node
  const int* nbb = g_nbr + (size_t)b * n * KNN;
  const float* ub = g_uu + (size_t)b * n * 96;
  const float* vb = g_vv + (size_t)b * n * 96;
  unsigned* eb = ekey + (size_t)b * n * HID;
  float ui0 = ub[(size_t)i * 96 + lane];
  float vi0 = vb[(size_t)i * 96 + lane];
  float ui1 = 0.f, vi1 = 0.f;
  if (lane < 32) {
    ui1 = ub[(size_t)i * 96 + 64 + lane];
    vi1 = vb[(size_t)i * 96 + 64 + lane];
  }
  const float biasv = sb2[lane];
  float macc = -1.0f;
  for (int k = 0; k < KNN; ++k) {
    __syncthreads();  // protect prev iteration's tv reads before overwrite
    int j = nbb[(size_t)i * KNN + k] & (n - 1);  // wave-uniform
    bool needB = true;
#pragma unroll
    for (int k2 = 0; k2 < KNN; ++k2)
      needB = needB && ((nbb[(size_t)j * KNN + k2] & (n - 1)) != i);
    {
      float vj0 = vb[(size_t)j * 96 + lane];
      float uj0 = ub[(size_t)j * 96 + lane];
      stA[wv][lane] = eluf(ui0 + vj0);
      if (needB) stB[wv][lane] = eluf(uj0 + vi0);
      if (lane < 32) {
        float vj1 = vb[(size_t)j * 96 + 64 + lane];
        float uj1 = ub[(size_t)j * 96 + 64 + lane];
        stA[wv][64 + lane] = eluf(ui1 + vj1);
        if (needB) stB[wv][64 + lane] = eluf(uj1 + vi1);
      }
    }
    __syncthreads();  // make tv visible across lanes
    float a0 = 0.f, a1 = 0.f, b0 = 0.f, b1 = 0.f;
    if (needB) {
      for (int kk = 0; kk < 96; kk += 4) {
        float4 ta = *(const float4*)&stA[wv][kk];
        float4 tb = *(const float4*)&stB[wv][kk];
        float w0 = sw2[(kk + 0) * 64 + lane];
        float w1 = sw2[(kk + 1) * 64 + lane];
        float w2v = sw2[(kk + 2) * 64 + lane];
        float w3 = sw2[(kk + 3) * 64 + lane];
        a0 += ta.x * w0 + ta.y * w1;
        a1 += ta.z * w2v + ta.w * w3;
        b0 += tb.x * w0 + tb.y * w1;
        b1 += tb.z * w2v + tb.w * w3;
      }
      atomicMax(&eb[(size_t)j * HID + lane],
                enc_safe(eluf(biasv + b0 + b1)));
    } else {
      for (int kk = 0; kk < 96; kk += 4) {
        float4 ta = *(const float4*)&stA[wv][kk];
        float w0 = sw2[(kk + 0) * 64 + lane];
        float w1 = sw2[(kk + 1) * 64 + lane];
        float w2v = sw2[(kk + 2) * 64 + lane];
        float w3 = sw2[(kk + 3) * 64 + lane];
        a0 += ta.x * w0 + ta.y * w1;
        a1 += ta.z * w2v + ta.w * w3;
      }
    }
    macc = fmaxf(macc, eluf(biasv + a0 + a1));
  }
  atomicMax(&eb[(size_t)i * HID + lane], enc_safe(macc));
}

// ---------------- pairwise max pool + norms ----------------------------------
__global__ __launch_bounds__(256) void pool_kernel() {
  int node = blockIdx.x * 256 + threadIdx.x;  // < BATCH*N2
  int b = node >> 11;
  int m = node & (N2 - 1);
  const unsigned* e = g_ek1 + ((size_t)b * N1 + 2 * m) * HID;
  float* hr = g_h2 + (size_t)node * HID;
  float sq = 0.f;
#pragma unroll
  for (int d = 0; d < HID; ++d) {
    float mx = fmaxf(dec_safe(e[d]), dec_safe(e[HID + d]));
    hr[d] = mx;
    sq += mx * mx;
  }
  g_x2n2[node] = sq;
}

// ---------------- global max + output MLP -> FLOAT32 output ------------------
__global__ __launch_bounds__(64) void final_kernel(
    const float* __restrict__ wo1, const float* __restrict__ bo1,
    const float* __restrict__ wo2, const float* __restrict__ bo2,
    const float* __restrict__ wo3, const float* __restrict__ bo3,
    float* __restrict__ out) {
  __shared__ float g[HID];
  __shared__ float o1s[HID];
  __shared__ float o2s[32];
  int b = blockIdx.x;
  int t = threadIdx.x;  // 0..63
  const unsigned* e = g_ek2 + (size_t)b * N2 * HID;
  unsigned mk = 0u;
  for (int m = 0; m < N2; ++m) {
    unsigned q = e[(size_t)m * HID + t];
    mk = q > mk ? q : mk;
  }
  g[t] = dec_safe(mk);
  __syncthreads();
  {
    float a1 = bo1[t];
    for (int d = 0; d < HID; ++d) a1 += g[d] * wo1[d * HID + t];
    o1s[t] = eluf(a1);
  }
  __syncthreads();
  if (t < 32) {
    float a2 = bo2[t];
    for (int d = 0; d < HID; ++d) a2 += o1s[d] * wo2[d * 32 + t];
    o2s[t] = eluf(a2);
  }
  __syncthreads();
  if (t == 0) {
    float acc0 = bo3[0];
    float acc1 = bo3[1];
    for (int d = 0; d < 32; ++d) {
      acc0 += o2s[d] * wo3[d * 2 + 0];
      acc1 += o2s[d] * wo3[d * 2 + 1];
    }
    float met = fmaxf(acc0, 0.f) + log1pf(expf(-fabsf(acc0)));      // softplus
    float phi = 3.14159265358979f * (2.f / (1.f + expf(-acc1)) - 1.f);
    out[b * 2 + 0] = met;
    out[b * 2 + 1] = phi;
  }
}

extern "C" void kernel_launch(void* const* d_in, const int* in_sizes, int n_in,
                              void* d_out, int out_size, void* d_ws,
                              size_t ws_size, hipStream_t stream) {
  const float* x     = (const float*)d_in[0];
  const float* dnorm = (const float*)d_in[1];
  const float* w_in1 = (const float*)d_in[2];
  const float* b_in1 = (const float*)d_in[3];
  const float* w_in2 = (const float*)d_in[4];
  const float* b_in2 = (const float*)d_in[5];
  const float* w_c1a = (const float*)d_in[6];
  const float* b_c1a = (const float*)d_in[7];
  const float* w_c1b = (const float*)d_in[8];
  const float* b_c1b = (const float*)d_in[9];
  const float* w_c2a = (const float*)d_in[10];
  const float* b_c2a = (const float*)d_in[11];
  const float* w_c2b = (const float*)d_in[12];
  const float* b_c2b = (const float*)d_in[13];
  const float* w_o1  = (const float*)d_in[14];
  const float* b_o1  = (const float*)d_in[15];
  const float* w_o2  = (const float*)d_in[16];
  const float* b_o2  = (const float*)d_in[17];
  const float* w_o3  = (const float*)d_in[18];
  const float* b_o3  = (const float*)d_in[19];

  init_kernel<<<(BATCH * N1 * HID + BATCH * N2 * HID) / 4 / 256, 256, 0,
                stream>>>();
  input_mlp<<<BATCH * N1 / 256, 256, 0, stream>>>(x, dnorm, w_in1, b_in1,
                                                  w_in2, b_in2);
  knn_kernel<0, 2><<<8 * (N1 / 128), 512, 0, stream>>>();
  uv_kernel<<<8 * (N1 / 64), 256, 0, stream>>>(0, w_c1a, b_c1a);
  edge_kernel<<<8 * (N1 / 4), 256, 0, stream>>>(0, w_c1b, b_c1b);
  pool_kernel<<<BATCH * N2 / 256, 256, 0, stream>>>();
  knn_kernel<1, 1><<<8 * (N2 / 64), 512, 0, stream>>>();
  uv_kernel<<<8 * (N2 / 64), 256, 0, stream>>>(1, w_c2a, b_c2a);
  edge_kernel<<<8 * (N2 / 4), 256, 0, stream>>>(1, w_c2b, b_c2b);
  final_kernel<<<BATCH, 64, 0, stream>>>(w_o1, b_o1, w_o2, b_o2, w_o3, b_o3,
                                         (float*)d_out);
}